// Round 2
// baseline (260.543 us; speedup 1.0000x reference)
//
#include <hip/hip_runtime.h>

// int4-dequant GEMM: y[m,n] = sum_k x[m,k] * scale[n, k/128] * (q[n,k] - 8)
// x: (512,4096) f32 | weight_packed: (11008,2048) int32 (2 nibbles in low byte) |
// scales: (11008,32) f32 | out: (512,11008) f32
//
// R9: structural fix of R8 (geometry unchanged: BM=128 BN=64 BK=64, 4 waves of
// 64x32, KS=1, 688 blocks, XCD-grouped swizzle). R8 was latency-bound
// (MfmaUtil 15.7 / VALU 28.6 / Occ 24 / HBM 13% - all low): 2 barriers/iter,
// vmcnt(0) drain right after bar2 with nothing to hide it.
// R9 = T3 minimum 2-phase pipeline: LDS double-buffer, ONE barrier per K-iter.
//   per iter: issue LOAD(k+1) -> MFMA(buf c) [hides load latency]
//             -> DEQ+WRITE(buf c^1) [no WAR: disjoint buffer] -> bar
// Plus T5 setprio(1) around the MFMA cluster (phase-diverse schedule now).
// Preserved verified pieces: dequant sequence, PAD=8 zero-conflict LDS layout
// (measured SQ_LDS_BANK_CONFLICT=0), 32x32x16 C/D store mapping
// (col=lane&31, row=(r&3)+8*(r>>2)+4*(lane>>5)).

typedef __attribute__((ext_vector_type(8)))  short short8;   // 32x32x16 A/B frag
typedef __attribute__((ext_vector_type(16))) float f32x16;   // 32x32x16 C/D frag
typedef __attribute__((ext_vector_type(4)))  float f32x4;
typedef __attribute__((ext_vector_type(4)))  int   i32x4;
typedef __attribute__((ext_vector_type(2)))  int   i32x2;

#define M_DIM 512
#define N_DIM 11008
#define K_DIM 4096
#define BM 128
#define BN 64
#define BK 64
#define PAD 8            // row stride 144B: measured 0 conflicts (R5)
#define THREADS 256
#define NTILE_M (M_DIM / BM)        // 4
#define NTILE_N (N_DIM / BN)        // 172
#define NTILES  (NTILE_M * NTILE_N) // 688 = 8 XCDs * 86
#define KITERS  (K_DIM / BK)        // 64

#if defined(__has_builtin)
#  if __has_builtin(__builtin_amdgcn_cvt_pk_bf16_f32)
#    define HAVE_PK_BF16 1
#  endif
#endif
#ifndef HAVE_PK_BF16
#  define HAVE_PK_BF16 0
#endif

__device__ __forceinline__ unsigned int fbits(float f) {
    union { float f; unsigned int u; } c; c.f = f; return c.u;
}
__device__ __forceinline__ int pack2bf(float lo, float hi) {  // [hi|lo] bf16, RNE
#if HAVE_PK_BF16
    typedef __attribute__((ext_vector_type(2))) __bf16 bf16x2;
    bf16x2 p = __builtin_amdgcn_cvt_pk_bf16_f32(lo, hi);
    int r; __builtin_memcpy(&r, &p, 4);
    return r;
#else
    unsigned int ul = fbits(lo), uh = fbits(hi);
    unsigned int l = (ul + 0x7FFFu + ((ul >> 16) & 1u)) >> 16;
    unsigned int h = (uh + 0x7FFFu + ((uh >> 16) & 1u)) & 0xFFFF0000u;
    return (int)(h | l);
#endif
}

// ---- x f32 -> bf16 workspace ----
__global__ __launch_bounds__(THREADS)
void cvt_x(const float* __restrict__ x, unsigned short* __restrict__ xw)
{
    int idx = (blockIdx.x * THREADS + threadIdx.x) * 4;
    f32x4 v = *(const f32x4*)(x + idx);
    i32x2 p;
    p[0] = pack2bf(v[0], v[1]);
    p[1] = pack2bf(v[2], v[3]);
    *(i32x2*)(xw + idx) = p;
}

// ---- main GEMM: 128x64 tile, 4 waves of 64x32, 32x32x16 MFMA, KS=1 ----
template<bool PRECVT>
__global__ __launch_bounds__(THREADS, 2)
void dq_gemm(const unsigned short* __restrict__ xw,
             const float* __restrict__ xf,
             const int* __restrict__ wp,
             const float* __restrict__ scales,
             float* __restrict__ out)
{
    // double-buffered: 2 x 27.6 KB = 55.3 KB -> 2 blocks/CU
    __shared__ __align__(16) unsigned short sA[2][BM][BK + PAD];
    __shared__ __align__(16) unsigned short sB[2][BN][BK + PAD];

    const int t  = threadIdx.x;
    const int bx = blockIdx.x;

    // Bijective XCD-grouped mapping: bx -> (nb, m_idx).
    // xcd = bx&7 (dispatch round-robins %8); w = bx>>3 in [0,86);
    // m_lo = w&1; p = w>>1 in [0,43); g = p*8+xcd in [0,344);
    // nb = g>>1; m = (g&1)*2 + m_lo. For fixed (xcd,p) both m_lo values share
    // (nb, m-pair) -> the 512 KB weight panel is reused within one XCD's L2.
    const int xcd = bx & 7;
    const int w   = bx >> 3;
    const int g_  = (w >> 1) * 8 + xcd;
    const int nb  = g_ >> 1;
    const int m_idx = ((g_ & 1) << 1) | (w & 1);

    const int m0 = m_idx * BM;
    const int n0 = nb * BN;

    const int wave = t >> 6;
    const int lane = t & 63;
    const int wm = (wave & 1) * 64;    // 2 m-waves
    const int wn = (wave >> 1) * 32;   // 2 n-waves
    const int lr = lane & 31;          // frag row
    const int lk = (lane >> 5) * 8;    // frag k

    // staging decomposition (c = i*256 + t):
    const int tr3 = t >> 3;            // row base within 32-row stripe
    const int tc8 = (t & 7) * 8;       // A col (shorts), 16B chunk
    const int tc4 = (t & 7) * 4;       // B col (ints),   16B chunk

    // T14 prefetch registers
    i32x4 pa[4];           // PRECVT path: 4 x 16B of bf16 A
    f32x4 paf[8];          // fallback path: 8 x 16B of f32 A
    i32x4 pb[2];
    float sc[2];

    auto LOAD = [&](int kk) {
        const int kb = kk * BK;
        if constexpr (PRECVT) {
            #pragma unroll
            for (int i = 0; i < 4; ++i)
                pa[i] = *(const i32x4*)(xw + (size_t)(m0 + i * 32 + tr3) * K_DIM + kb + tc8);
        } else {
            #pragma unroll
            for (int i = 0; i < 8; ++i) {
                int row = i * 16 + (t >> 4), col = (t & 15) * 4;
                paf[i] = *(const f32x4*)(xf + (size_t)(m0 + row) * K_DIM + kb + col);
            }
        }
        const int gq = kb >> 7;
        #pragma unroll
        for (int i = 0; i < 2; ++i) {
            pb[i] = *(const i32x4*)(wp + (size_t)(n0 + i * 32 + tr3) * (K_DIM / 2) + (kb >> 1) + tc4);
            sc[i] = scales[(size_t)(n0 + i * 32 + tr3) * (K_DIM / 128) + gq];
        }
    };

    auto WRITE = [&](int buf) {
        if constexpr (PRECVT) {
            #pragma unroll
            for (int i = 0; i < 4; ++i)
                *(i32x4*)&sA[buf][i * 32 + tr3][tc8] = pa[i];
        } else {
            #pragma unroll
            for (int i = 0; i < 8; ++i) {
                int row = i * 16 + (t >> 4), col = (t & 15) * 4;
                i32x2 p;
                p[0] = pack2bf(paf[i][0], paf[i][1]);
                p[1] = pack2bf(paf[i][2], paf[i][3]);
                *(i32x2*)&sA[buf][row][col] = p;
            }
        }
        #pragma unroll
        for (int i = 0; i < 2; ++i) {
            float s = sc[i], ns8 = s * -8.0f;
            i32x4 res;
            #pragma unroll
            for (int e = 0; e < 4; ++e) {
                int b = pb[i][e];
                res[e] = pack2bf((float)(b & 15) * s + ns8,
                                 (float)((b >> 4) & 15) * s + ns8);
            }
            *(i32x4*)&sB[buf][i * 32 + tr3][tc4 * 2] = res;
        }
    };

    f32x16 acc[2] = {};

    auto MFMA_PHASE = [&](int buf) {
        __builtin_amdgcn_s_setprio(1);
        #pragma unroll
        for (int ks = 0; ks < BK; ks += 16) {
            short8 a[2], b;
            #pragma unroll
            for (int i = 0; i < 2; ++i)
                a[i] = *(const short8*)&sA[buf][wm + i * 32 + lr][ks + lk];
            b = *(const short8*)&sB[buf][wn + lr][ks + lk];
            #pragma unroll
            for (int i = 0; i < 2; ++i)
                acc[i] = __builtin_amdgcn_mfma_f32_32x32x16_bf16(a[i], b, acc[i], 0, 0, 0);
        }
        __builtin_amdgcn_s_setprio(0);
    };

    // prologue: tile 0 -> buf 0
    LOAD(0);
    WRITE(0);
    __syncthreads();

    // steady state: ONE barrier per K-iter.
    // iter kk: tile kk lives in buf (kk&1); write tile kk+1 into buf (kk&1)^1.
    #pragma unroll 2
    for (int kk = 0; kk < KITERS - 1; ++kk) {
        const int cur = kk & 1;
        LOAD(kk + 1);            // 8 VMEM in flight across the MFMA phase
        MFMA_PHASE(cur);         // ds_read + MFMA on buf cur
        WRITE(cur ^ 1);          // vmcnt drains here; disjoint buffer, no WAR
        __syncthreads();         // tile kk+1 visible; everyone left buf cur
    }
    MFMA_PHASE((KITERS - 1) & 1);   // tile 63 in buf 1

    // direct store: C/D col=lane&31, row=(r&3)+8*(r>>2)+4*(lane>>5)
    const int rbase = (lane >> 5) * 4;
    #pragma unroll
    for (int i = 0; i < 2; ++i) {
        int mg0 = m0 + wm + i * 32 + rbase;
        int ng  = n0 + wn + lr;
        #pragma unroll
        for (int r = 0; r < 16; ++r)
            out[(size_t)(mg0 + (r & 3) + 8 * (r >> 2)) * N_DIM + ng] = acc[i][r];
    }
}

extern "C" void kernel_launch(void* const* d_in, const int* in_sizes, int n_in,
                              void* d_out, int out_size, void* d_ws, size_t ws_size,
                              hipStream_t stream) {
    (void)in_sizes; (void)n_in; (void)out_size;
    const float* x      = (const float*)d_in[0];
    const int*   wpck   = (const int*)d_in[1];
    const float* scales = (const float*)d_in[2];
    float*       out    = (float*)d_out;

    const size_t XW_BYTES = (size_t)M_DIM * K_DIM * 2;   // 4 MB

    if (ws_size >= XW_BYTES) {
        unsigned short* xw = (unsigned short*)d_ws;
        cvt_x<<<(M_DIM * K_DIM) / (THREADS * 4), THREADS, 0, stream>>>(x, xw);
        dq_gemm<true><<<NTILES, THREADS, 0, stream>>>(xw, x, wpck, scales, out);
    } else {
        dq_gemm<false><<<NTILES, THREADS, 0, stream>>>(nullptr, x, wpck, scales, out);
    }
}

// Round 3
// 254.610 us; speedup vs baseline: 1.0233x; 1.0233x over previous
//
#include <hip/hip_runtime.h>

// int4-dequant GEMM: y[m,n] = sum_k x[m,k] * scale[n, k/128] * (q[n,k] - 8)
// x: (512,4096) f32 | weight_packed: (11008,2048) int32 (2 nibbles in low byte) |
// scales: (11008,32) f32 | out: (512,11008) f32
//
// R10: A never touches LDS. cvt_x writes xw in MFMA-FRAGMENT layout:
// chunk index c = (mb*256 + kb)*64 + lane (mb = m/32, kb = k/16), each chunk =
// lane's 16B A-fragment (m = mb*32 + (lane&31), k = kb*16 + (lane>>5)*8 .. +8).
// GEMM loads A as ONE coalesced global_load_dwordx4 per fragment straight from
// L2 (x = 4 MB bf16, L2-resident; ~688 MB aggregate L2 traffic ~ 11 TB/s << 34.5).
// R9 post-mortem: LDS pipe was the floor (72 LDS instrs/block-iter ~ 860 cyc vs
// 64 cyc MFMA wall) and 55 KB LDS killed residency. R10: LDS = B only,
// double-buffered 2x9.2 KB -> 24 LDS instrs/block-iter, 3+ blocks/CU.
// Geometry unchanged: BM=128 BN=64 BK=64, 4 waves of 64x32, KS=1, 688 blocks,
// XCD-grouped bijective swizzle. Verified pieces preserved: dequant sequence,
// PAD=8 zero-conflict sB layout, 32x32x16 C/D mapping
// (col=lane&31, row=(r&3)+8*(r>>2)+4*(lane>>5)).

typedef __attribute__((ext_vector_type(8)))  short short8;   // 32x32x16 A/B frag
typedef __attribute__((ext_vector_type(16))) float f32x16;   // 32x32x16 C/D frag
typedef __attribute__((ext_vector_type(4)))  float f32x4;
typedef __attribute__((ext_vector_type(4)))  int   i32x4;
typedef __attribute__((ext_vector_type(2)))  int   i32x2;

#define M_DIM 512
#define N_DIM 11008
#define K_DIM 4096
#define BM 128
#define BN 64
#define BK 64
#define PAD 8            // B row stride 144B: measured 0 conflicts (R5..R9)
#define THREADS 256
#define NTILE_M (M_DIM / BM)        // 4
#define NTILE_N (N_DIM / BN)        // 172
#define NTILES  (NTILE_M * NTILE_N) // 688 = 8 XCDs * 86
#define KITERS  (K_DIM / BK)        // 64
#define KB16    (K_DIM / 16)        // 256 k-subtiles per m-stripe

#if defined(__has_builtin)
#  if __has_builtin(__builtin_amdgcn_cvt_pk_bf16_f32)
#    define HAVE_PK_BF16 1
#  endif
#endif
#ifndef HAVE_PK_BF16
#  define HAVE_PK_BF16 0
#endif

__device__ __forceinline__ unsigned int fbits(float f) {
    union { float f; unsigned int u; } c; c.f = f; return c.u;
}
__device__ __forceinline__ int pack2bf(float lo, float hi) {  // [hi|lo] bf16, RNE
#if HAVE_PK_BF16
    typedef __attribute__((ext_vector_type(2))) __bf16 bf16x2;
    bf16x2 p = __builtin_amdgcn_cvt_pk_bf16_f32(lo, hi);
    int r; __builtin_memcpy(&r, &p, 4);
    return r;
#else
    unsigned int ul = fbits(lo), uh = fbits(hi);
    unsigned int l = (ul + 0x7FFFu + ((ul >> 16) & 1u)) >> 16;
    unsigned int h = (uh + 0x7FFFu + ((uh >> 16) & 1u)) & 0xFFFF0000u;
    return (int)(h | l);
#endif
}

// ---- x f32 -> bf16 fragment-layout workspace ----
// chunk c in [0, M*K/8): lane=c&63, kb=(c>>6)&255, mb=c>>14
// m = mb*32 + (lane&31), k = kb*16 + (lane>>5)*8
__global__ __launch_bounds__(THREADS)
void cvt_x(const float* __restrict__ x, unsigned short* __restrict__ xw)
{
    int c    = blockIdx.x * THREADS + threadIdx.x;
    int lane = c & 63;
    int kb   = (c >> 6) & (KB16 - 1);
    int mb   = c >> 14;
    int m    = mb * 32 + (lane & 31);
    int k    = kb * 16 + (lane >> 5) * 8;

    const float* src = x + (size_t)m * K_DIM + k;
    f32x4 v0 = *(const f32x4*)(src);
    f32x4 v1 = *(const f32x4*)(src + 4);
    i32x4 p;
    p[0] = pack2bf(v0[0], v0[1]);
    p[1] = pack2bf(v0[2], v0[3]);
    p[2] = pack2bf(v1[0], v1[1]);
    p[3] = pack2bf(v1[2], v1[3]);
    *(i32x4*)(xw + (size_t)c * 8) = p;
}

// ---- main GEMM: 128x64 tile, 4 waves of 64x32, 32x32x16 MFMA, KS=1 ----
template<bool PRECVT>
__global__ __launch_bounds__(THREADS, 3)
void dq_gemm(const unsigned short* __restrict__ xw,
             const float* __restrict__ xf,
             const int* __restrict__ wp,
             const float* __restrict__ scales,
             float* __restrict__ out)
{
    // B only, double-buffered: 2 x 9.2 KB = 18.4 KB
    __shared__ __align__(16) unsigned short sB[2][BN][BK + PAD];

    const int t  = threadIdx.x;
    const int bx = blockIdx.x;

    // Bijective XCD-grouped mapping: bx -> (nb, m_idx). For fixed (xcd, p) the
    // two m_lo values share the same 512 KB weight panel -> XCD-L2 reuse.
    const int xcd = bx & 7;
    const int w   = bx >> 3;
    const int g_  = (w >> 1) * 8 + xcd;
    const int nb  = g_ >> 1;
    const int m_idx = ((g_ & 1) << 1) | (w & 1);

    const int m0 = m_idx * BM;
    const int n0 = nb * BN;

    const int wave = t >> 6;
    const int lane = t & 63;
    const int wm = (wave & 1) * 64;    // 2 m-waves
    const int wn = (wave >> 1) * 32;   // 2 n-waves
    const int lr = lane & 31;          // frag row
    const int lk = (lane >> 5) * 8;    // frag k

    // B staging decomposition
    const int tr3 = t >> 3;            // row base within 32-row stripe [0,32)
    const int tc4 = (t & 7) * 4;       // B col (ints), 16B chunk

    i32x4 pb[2];
    float sc[2];

    auto LOADB = [&](int kk) {
        const int kb = kk * BK;
        const int gq = kb >> 7;
        #pragma unroll
        for (int i = 0; i < 2; ++i) {
            pb[i] = *(const i32x4*)(wp + (size_t)(n0 + i * 32 + tr3) * (K_DIM / 2) + (kb >> 1) + tc4);
            sc[i] = scales[(size_t)(n0 + i * 32 + tr3) * (K_DIM / 128) + gq];
        }
    };

    auto WRITEB = [&](int buf) {
        #pragma unroll
        for (int i = 0; i < 2; ++i) {
            float s = sc[i], ns8 = s * -8.0f;
            i32x4 res;
            #pragma unroll
            for (int e = 0; e < 4; ++e) {
                int b = pb[i][e];
                res[e] = pack2bf((float)(b & 15) * s + ns8,
                                 (float)((b >> 4) & 15) * s + ns8);
            }
            *(i32x4*)&sB[buf][i * 32 + tr3][tc4 * 2] = res;
        }
    };

    f32x16 acc[2] = {};

    // A fragment base: chunk index = (mb*256 + kb16)*64 + lane
    const short8* xa8 = (const short8*)xw;
    const size_t abase = ((size_t)((m0 + wm) >> 5) * KB16) * 64 + lane;

    auto MFMA_PHASE = [&](int buf, int kb) {
        __builtin_amdgcn_s_setprio(1);
        #pragma unroll
        for (int ks = 0; ks < BK; ks += 16) {
            short8 a[2], b;
            if constexpr (PRECVT) {
                const size_t ab = abase + (size_t)((kb + ks) >> 4) * 64;
                a[0] = xa8[ab];
                a[1] = xa8[ab + (size_t)KB16 * 64];
            } else {
                #pragma unroll
                for (int i = 0; i < 2; ++i) {
                    const float* src = xf + (size_t)(m0 + wm + i * 32 + lr) * K_DIM + kb + ks + lk;
                    f32x4 v0 = *(const f32x4*)(src);
                    f32x4 v1 = *(const f32x4*)(src + 4);
                    i32x4 p;
                    p[0] = pack2bf(v0[0], v0[1]);
                    p[1] = pack2bf(v0[2], v0[3]);
                    p[2] = pack2bf(v1[0], v1[1]);
                    p[3] = pack2bf(v1[2], v1[3]);
                    __builtin_memcpy(&a[i], &p, 16);
                }
            }
            b = *(const short8*)&sB[buf][wn + lr][ks + lk];
            acc[0] = __builtin_amdgcn_mfma_f32_32x32x16_bf16(a[0], b, acc[0], 0, 0, 0);
            acc[1] = __builtin_amdgcn_mfma_f32_32x32x16_bf16(a[1], b, acc[1], 0, 0, 0);
        }
        __builtin_amdgcn_s_setprio(0);
    };

    // prologue: tile 0 -> buf 0
    LOADB(0);
    WRITEB(0);
    __syncthreads();

    // steady state: ONE barrier per K-iter; A-loads are barrier-free VMEM.
    for (int kk = 0; kk < KITERS - 1; ++kk) {
        const int cur = kk & 1;
        LOADB(kk + 1);           // 2 dwordx4 + 2 scales in flight across MFMA
        MFMA_PHASE(cur, kk * BK);
        WRITEB(cur ^ 1);         // vmcnt drains here; disjoint buffer, no WAR
        __syncthreads();
    }
    MFMA_PHASE((KITERS - 1) & 1, (KITERS - 1) * BK);

    // direct store: C/D col=lane&31, row=(r&3)+8*(r>>2)+4*(lane>>5)
    const int rbase = (lane >> 5) * 4;
    #pragma unroll
    for (int i = 0; i < 2; ++i) {
        int mg0 = m0 + wm + i * 32 + rbase;
        int ng  = n0 + wn + lr;
        #pragma unroll
        for (int r = 0; r < 16; ++r)
            out[(size_t)(mg0 + (r & 3) + 8 * (r >> 2)) * N_DIM + ng] = acc[i][r];
    }
}

extern "C" void kernel_launch(void* const* d_in, const int* in_sizes, int n_in,
                              void* d_out, int out_size, void* d_ws, size_t ws_size,
                              hipStream_t stream) {
    (void)in_sizes; (void)n_in; (void)out_size;
    const float* x      = (const float*)d_in[0];
    const int*   wpck   = (const int*)d_in[1];
    const float* scales = (const float*)d_in[2];
    float*       out    = (float*)d_out;

    const size_t XW_BYTES = (size_t)M_DIM * K_DIM * 2;   // 4 MB

    if (ws_size >= XW_BYTES) {
        unsigned short* xw = (unsigned short*)d_ws;
        cvt_x<<<(M_DIM * K_DIM) / (THREADS * 8), THREADS, 0, stream>>>(x, xw);
        dq_gemm<true><<<NTILES, THREADS, 0, stream>>>(xw, x, wpck, scales, out);
    } else {
        dq_gemm<false><<<NTILES, THREADS, 0, stream>>>(nullptr, x, wpck, scales, out);
    }
}